// Round 19
// baseline (505.017 us; speedup 1.0000x reference)
//
#include <hip/hip_runtime.h>

#define F      8192
#define KD     64     // coordinate dimensionality
#define NB     8      // neighbors
#define WROWS  32     // rows per block (R13: 16 regressed; 32 verified optimal)
#define MKEEP  16     // per-(row,quarter) approx list length (superset of top-8)
#define JQ     4      // column quarters
#define CPR    64     // cols per block-round (4 waves x 16)
#define NROUND ((F / JQ) / CPR)   // 32
#define CAP    96     // per-row candidate buffer capacity per fold interval
#define MARGIN 0.25f  // >= 2x max |d_approx - d_exact| (fp16 worst-case ~0.08)
#define GRID   1024   // == guaranteed co-resident capacity (4 blocks/CU x 256 CUs)

typedef unsigned long long u64;
typedef unsigned short ushort_t;
typedef __attribute__((ext_vector_type(8))) _Float16 f16x8;  // 8 f16 = 4 VGPRs
typedef __attribute__((ext_vector_type(4))) float f32x4;

__device__ __forceinline__ u64 pack64(float d, int j) {
    // d >= 0 -> f32 bits order-preserving; u64 ascending == lex (d, j)
    return ((u64)__float_as_uint(d) << 32) | (unsigned)j;
}

// ---------------------------------------------------------------------------
// Software grid barrier, R19 fix. R18's spin used atomicAdd(rel,0) — an RMW:
// 1023 pollers serialize at the owning L2 with exclusive-ownership ping-pong
// (~60us/sweep -> ~290us total barrier cost, MfmaUtil 0.85% proved phases ran
// full speed). Fix: poll with device-scope atomic LOAD (no ownership, L1-
// bypassing coherent read) + short s_sleep. Release = atomic store RELEASE.
// Deadlock-safe: __launch_bounds__(256,4) + 33KB LDS -> >=4 blocks/CU ->
// all GRID=1024 blocks co-resident regardless of dispatch order.
// ---------------------------------------------------------------------------
__device__ __forceinline__ void gbar(unsigned* cnt, unsigned* rel) {
    __syncthreads();
    if (threadIdx.x == 0) {
        __threadfence();                         // release prior writes, device scope
        unsigned v = __hip_atomic_fetch_add(cnt, 1u, __ATOMIC_ACQ_REL,
                                            __HIP_MEMORY_SCOPE_AGENT);
        if (v == GRID - 1u) {
            __hip_atomic_store(rel, 1u, __ATOMIC_RELEASE, __HIP_MEMORY_SCOPE_AGENT);
        } else {
            while (__hip_atomic_load(rel, __ATOMIC_RELAXED,
                                     __HIP_MEMORY_SCOPE_AGENT) == 0u)
                __builtin_amdgcn_s_sleep(2);
        }
        __threadfence();                         // acquire
    }
    __syncthreads();
}

// ---------------------------------------------------------------------------
// DPP-based 16-lane exchanges (R5-verified). row_shr:N = dest[i] <- src[i-N];
// row_shl:N = dest[i] <- src[i+N]; quad_perm/mirror direction-symmetric.
// ---------------------------------------------------------------------------
template<int CTRL>
__device__ __forceinline__ u64 dpp_u64(u64 x) {
    unsigned lo = (unsigned)x, hi = (unsigned)(x >> 32);
    lo = (unsigned)__builtin_amdgcn_update_dpp(0, (int)lo, CTRL, 0xF, 0xF, true);
    hi = (unsigned)__builtin_amdgcn_update_dpp(0, (int)hi, CTRL, 0xF, 0xF, true);
    return ((u64)hi << 32) | lo;
}
__device__ __forceinline__ u64 swap_xor1(u64 x) { return dpp_u64<0xB1>(x); }
__device__ __forceinline__ u64 swap_xor2(u64 x) { return dpp_u64<0x4E>(x); }
__device__ __forceinline__ u64 swap_xor4(u64 x, int n) {
    u64 shr = dpp_u64<0x114>(x);   // src[n-4]
    u64 shl = dpp_u64<0x104>(x);   // src[n+4]
    return (n & 4) ? shr : shl;
}
__device__ __forceinline__ u64 swap_xor8(u64 x, int n) {
    u64 shr = dpp_u64<0x118>(x);   // src[n-8]
    u64 shl = dpp_u64<0x108>(x);   // src[n+8]
    return (n & 8) ? shr : shl;
}
__device__ __forceinline__ u64 swap_mirror(u64 x) { return dpp_u64<0x140>(x); }
// cross-quad exchange within a 32-lane half: ds_swizzle BitMode xor 16 (0x401F)
__device__ __forceinline__ u64 swz_xor16(u64 x) {
    unsigned lo = (unsigned)__builtin_amdgcn_ds_swizzle((int)(unsigned)x, 0x401F);
    unsigned hi = (unsigned)__builtin_amdgcn_ds_swizzle((int)(x >> 32), 0x401F);
    return ((u64)hi << 32) | lo;
}

// compare-exchange stages (ascending bitonic over lanes n=0..15)
#define CEK(x, J, K, SW)                                                      \
    { u64 px = SW; bool wmin = ((n & (J)) == 0) == ((n & (K)) == 0);          \
      x = (wmin == (px < x)) ? px : x; }
#define CEA(L, J, SW)                                                         \
    { u64 pl = SW; bool wmin = ((n & (J)) == 0);                              \
      L = (wmin == (pl < L)) ? pl : L; }
#define SORT16(x)                                                             \
    CEK(x, 1, 2,  swap_xor1(x))                                               \
    CEK(x, 2, 4,  swap_xor2(x))    CEK(x, 1, 4,  swap_xor1(x))                \
    CEK(x, 4, 8,  swap_xor4(x,n))  CEK(x, 2, 8,  swap_xor2(x))                \
    CEK(x, 1, 8,  swap_xor1(x))                                               \
    CEK(x, 8, 16, swap_xor8(x,n))  CEK(x, 4, 16, swap_xor4(x,n))              \
    CEK(x, 2, 16, swap_xor2(x))    CEK(x, 1, 16, swap_xor1(x))
// merge-with-descending-partner then 4-stage clean (list stays sorted asc)
#define MERGECLEAN(x, Y)                                                      \
    { u64 y = (Y); x = (y < x) ? y : x;                                       \
      CEA(x, 8, swap_xor8(x, n))                                              \
      CEA(x, 4, swap_xor4(x, n))                                              \
      CEA(x, 2, swap_xor2(x))                                                 \
      CEA(x, 1, swap_xor1(x)) }

// ---------------------------------------------------------------------------
// R19: fused kernel with load-polling barrier. Phase bodies verbatim from
// R16-verified kernels. A_s moved OUT of the union (33KB total, still
// 4 blocks/CU) so gather's row staging overlaps phase-3 stragglers.
// Decision rule: total >= 163.5 (R16) -> abandon fusion, revert to R16.
// ---------------------------------------------------------------------------
__global__ __launch_bounds__(256, 4) void fused_kernel(
        const float* __restrict__ inp, const float* __restrict__ crd,
        float* __restrict__ out, ushort_t* __restrict__ XtH,
        float* __restrict__ Xt32, float* __restrict__ sq,
        int* __restrict__ knn, u64* __restrict__ part,
        unsigned* __restrict__ bar) {
    __shared__ union ShMem {
        struct {
            u64 buf[WROWS][CAP + 1];     // 24.8 KB
            u64 lst[WROWS][MKEEP + 1];   // 4.4 KB
            float thr[WROWS];
            int cnt[WROWS];
        } k;
        float row[F];                    // 32 KB (gather)
    } sh;
    __shared__ float A_s[4][KD];         // 1 KB (recheck; outside union)

    const int bid  = blockIdx.x;
    const int tid  = threadIdx.x;
    const int wave = tid >> 6;
    const int tx   = tid & 63;
    const int quad = tx >> 4;
    const int n    = tx & 15;

    // ======================= phase 1: prep (32 active blocks) ==============
    if (bid < F / 256) {
        const int f = bid * 256 + tid;
        float acc = 0.f;
#pragma unroll
        for (int kb = 0; kb < 8; ++kb) {
            ushort_t hb[8];
            float    xv[8];
#pragma unroll
            for (int u = 0; u < 8; ++u) {
                int k = kb * 8 + u;
                float x = crd[k * F + f];
                acc = fmaf(x, x, acc);                       // exact ascending-k chain
                hb[u] = __builtin_bit_cast(ushort_t, (_Float16)x);  // RTN f32->f16
                xv[u] = x;
            }
            *(uint4*)&XtH[(size_t)f * KD + kb * 8] = *(const uint4*)hb;
            *(float4*)&Xt32[(size_t)f * KD + kb * 8]     = *(const float4*)&xv[0];
            *(float4*)&Xt32[(size_t)f * KD + kb * 8 + 4] = *(const float4*)&xv[4];
        }
        sq[f] = acc;
    }
    gbar(&bar[0], &bar[1]);

    // ======================= phase 2: knn (R8-verified body) ===============
    {
        const int blockRow = (bid >> 2) * WROWS;
        const int jq    = bid & 3;
        const int jbase = jq * (F / JQ);

        if (tid < WROWS) { sh.k.cnt[tid] = 0; sh.k.thr[tid] = __int_as_float(0x7f800000); }
#pragma unroll
        for (int e = tid; e < WROWS * MKEEP; e += 256) sh.k.lst[e >> 4][e & 15] = ~0ULL;
        __syncthreads();

        const size_t a0 = (size_t)(blockRow + n) * KD + quad * 8;
        const size_t a1 = (size_t)(blockRow + 16 + n) * KD + quad * 8;
        const f16x8 a0h0 = *(const f16x8*)(XtH + a0), a0h1 = *(const f16x8*)(XtH + a0 + 32);
        const f16x8 a1h0 = *(const f16x8*)(XtH + a1), a1h1 = *(const f16x8*)(XtH + a1 + 32);
        const f32x4 sqi0 = *(const f32x4*)&sq[blockRow + quad * 4];
        const f32x4 sqi1 = *(const f32x4*)&sq[blockRow + 16 + quad * 4];
        f32x4 pre0, pre1;   // 0.5*(sqi - thr); -inf => accept-all
#pragma unroll
        for (int r = 0; r < 4; ++r) { pre0[r] = -__int_as_float(0x7f800000);
                                      pre1[r] = -__int_as_float(0x7f800000); }

        const int laneCol = wave * 16 + n;

#define LOADB(H0, H1, SJ, RND)                                                \
    {   int jc = jbase + (RND) * CPR + laneCol;                               \
        size_t bo = (size_t)jc * KD + quad * 8;                               \
        H0 = *(const f16x8*)(XtH + bo); H1 = *(const f16x8*)(XtH + bo + 32);  \
        SJ = sq[jc]; }

#define MFMABODY(H0, H1)                                                      \
        f32x4 za0 = {0,0,0,0}, za1 = {0,0,0,0};                               \
        za0 = __builtin_amdgcn_mfma_f32_16x16x32_f16(a0h0, H0, za0, 0, 0, 0); \
        za0 = __builtin_amdgcn_mfma_f32_16x16x32_f16(a0h1, H1, za0, 0, 0, 0); \
        za1 = __builtin_amdgcn_mfma_f32_16x16x32_f16(a1h0, H0, za1, 0, 0, 0); \
        za1 = __builtin_amdgcn_mfma_f32_16x16x32_f16(a1h1, H1, za1, 0, 0, 0);

#define PROCESS0(H0, H1, SJ, RND)                                             \
    {   MFMABODY(H0, H1)                                                      \
        const int jc = jbase + (RND) * CPR + laneCol;                         \
        _Pragma("unroll")                                                     \
        for (int r = 0; r < 4; ++r) {                                         \
            float d0 = fmaxf((sqi0[r] + SJ) - 2.f * za0[r], 0.f);             \
            sh.k.buf[quad * 4 + r][laneCol] = pack64(d0, jc);                 \
            float d1 = fmaxf((sqi1[r] + SJ) - 2.f * za1[r], 0.f);             \
            sh.k.buf[16 + quad * 4 + r][laneCol] = pack64(d1, jc);            \
        } }

#define PROCESS(H0, H1, SJ, RND)                                              \
    {   MFMABODY(H0, H1)                                                      \
        const int jc = jbase + (RND) * CPR + laneCol;                         \
        const float h = 0.5f * SJ;                                            \
        _Pragma("unroll")                                                     \
        for (int r = 0; r < 4; ++r) {                                         \
            float dot = za0[r];                                               \
            if (dot >= pre0[r] + h) {                                         \
                float d = fmaxf((sqi0[r] + SJ) - 2.f * dot, 0.f);             \
                int row = quad * 4 + r;                                       \
                int q = atomicAdd(&sh.k.cnt[row], 1);                         \
                if (q < CAP) sh.k.buf[row][q] = pack64(d, jc);                \
            }                                                                 \
            dot = za1[r];                                                     \
            if (dot >= pre1[r] + h) {                                         \
                float d = fmaxf((sqi1[r] + SJ) - 2.f * dot, 0.f);             \
                int row = 16 + quad * 4 + r;                                  \
                int q = atomicAdd(&sh.k.cnt[row], 1);                         \
                if (q < CAP) sh.k.buf[row][q] = pack64(d, jc);                \
            }                                                                 \
        } }

#define FOLD(R0)                                                              \
    {   __syncthreads();                                                      \
        _Pragma("unroll")                                                     \
        for (int p = 0; p < 2; ++p) {                                         \
            const int row = p * 16 + wave * 4 + quad;                         \
            u64 Lv = sh.k.lst[row][n];                                        \
            const u64 tmax = __shfl(Lv, (tx & 48) | 15, 64);                  \
            const int nn = (R0) ? CPR : min(sh.k.cnt[row], CAP);              \
            for (int ii = 0; ii < nn; ii += 16) {                             \
                u64 x = (ii + n < nn) ? sh.k.buf[row][ii + n] : ~0ULL;        \
                u64 bal = __ballot(x < tmax);                                 \
                if ((unsigned short)(bal >> (quad * 16)) == 0) continue;      \
                SORT16(x)                                                     \
                MERGECLEAN(Lv, swap_mirror(x))                                \
            }                                                                 \
            sh.k.lst[row][n] = Lv;                                            \
            if (n == NB - 1) sh.k.thr[row] = __uint_as_float((unsigned)(Lv >> 32)) + MARGIN; \
            if (n == 0) sh.k.cnt[row] = 0;                                    \
        }                                                                     \
        __syncthreads();                                                      \
        {   f32x4 t0 = *(const f32x4*)&sh.k.thr[quad * 4];                    \
            f32x4 t1 = *(const f32x4*)&sh.k.thr[16 + quad * 4];               \
            _Pragma("unroll")                                                 \
            for (int r = 0; r < 4; ++r) {                                     \
                pre0[r] = 0.5f * (sqi0[r] - t0[r]);                           \
                pre1[r] = 0.5f * (sqi1[r] - t1[r]);                           \
            } } }

        f16x8 B0h0, B0h1, B1h0, B1h1;
        float B0sj, B1sj;
        LOADB(B0h0, B0h1, B0sj, 0)
        LOADB(B1h0, B1h1, B1sj, 1)

        PROCESS0(B0h0, B0h1, B0sj, 0)
        LOADB(B0h0, B0h1, B0sj, 2)
        FOLD(1)
        PROCESS(B1h0, B1h1, B1sj, 1)
        LOADB(B1h0, B1h1, B1sj, 3)
        FOLD(0)

        for (int rr = 2; rr < NROUND; rr += 2) {
            PROCESS(B0h0, B0h1, B0sj, rr)
            if (rr + 2 < NROUND) LOADB(B0h0, B0h1, B0sj, rr + 2)
            PROCESS(B1h0, B1h1, B1sj, rr + 1)
            if (rr + 3 < NROUND) LOADB(B1h0, B1h1, B1sj, rr + 3)
            if (((rr + 1) & (rr + 2)) == 0) FOLD(0)   // rounds 3,7,15,31
        }

#pragma unroll
        for (int e = tid; e < WROWS * MKEEP; e += 256) {
            int rrw = e >> 4, ss = e & 15;
            part[((size_t)jq * F + blockRow + rrw) * MKEEP + ss] = sh.k.lst[rrw][ss];
        }
#undef LOADB
#undef MFMABODY
#undef PROCESS0
#undef PROCESS
#undef FOLD
    }
    gbar(&bar[2], &bar[3]);

    // ======================= phase 3: recheck (2 groups per block) =========
    for (int g = bid; g < F / 4; g += GRID) {
        const int rl = wave;
        const int i = g * 4 + rl;

        A_s[tid >> 6][tid & 63] = Xt32[(size_t)(g * 4 + (tid >> 6)) * KD + (tid & 63)];
        __syncthreads();

        u64 pc = part[((size_t)(tx >> 4) * F + i) * MKEEP + (tx & 15)];
        int j = (int)(pc & 0xffffffffu);

        const float4* b4 = (const float4*)(Xt32 + (size_t)j * KD);
        float acc = 0.f;
#pragma unroll
        for (int kk = 0; kk < KD / 4; ++kk) {
            float4 b = b4[kk];
            const float* a = &A_s[rl][kk * 4];
            acc = fmaf(a[0], b.x, acc);
            acc = fmaf(a[1], b.y, acc);
            acc = fmaf(a[2], b.z, acc);
            acc = fmaf(a[3], b.w, acc);
        }
        float d = fmaxf((sq[i] + sq[j]) - 2.f * acc, 0.f);
        u64 x = pack64(d, j);

        SORT16(x)
        MERGECLEAN(x, swz_xor16(swap_mirror(x)))
        MERGECLEAN(x, __shfl_xor(swap_mirror(x), 32, 64))

        if (tx < NB) knn[(size_t)i * NB + tx] = (int)(x & 0xffffffffu);
        __syncthreads();   // A_s reused next iteration
    }
    // overlap gather's row staging with phase-3 stragglers (row unions with
    // knn-phase LDS only; A_s is separate, so this is safe here)
    {
        const int bc = bid >> 2;
        const float4* in4  = (const float4*)(inp + (size_t)bc * F);
        float4*       row4 = (float4*)sh.row;
#pragma unroll
        for (int i2 = 0; i2 < (F / 4) / 256; ++i2) row4[i2 * 256 + tid] = in4[i2 * 256 + tid];
    }
    gbar(&bar[4], &bar[5]);

    // ======================= phase 4: gather (row already staged) ==========
    {
        const int bc    = bid >> 2;
        const int chunk = bid & 3;

        const int4* kn4 = (const int4*)knn;
        float4*     ou4 = (float4*)(out + (size_t)bc * (F * NB));

#pragma unroll
        for (int i2 = 0; i2 < 16; ++i2) {
            int e = chunk * 4096 + i2 * 256 + tid;
            int4 idx = kn4[e];
            if (e == 0) idx.x = 0;             // flat_idx[0] hardcoded 0
            float4 o;
            o.x = sh.row[idx.x]; o.y = sh.row[idx.y];
            o.z = sh.row[idx.z]; o.w = sh.row[idx.w];
            ou4[e] = o;
        }
    }
}

extern "C" void kernel_launch(void* const* d_in, const int* in_sizes, int n_in,
                              void* d_out, int out_size, void* d_ws, size_t ws_size,
                              hipStream_t stream) {
    const float* inp = (const float*)d_in[0];   // (64,4,8192,1) fp32
    const float* crd = (const float*)d_in[1];   // (64,1,8192)  fp32
    float* out = (float*)d_out;                 // (64,4,65536,1) fp32

    ushort_t* XtH  = (ushort_t*)d_ws;                               // 1 MB (fp16)
    unsigned* bar  = (unsigned*)((char*)d_ws + (1u << 20));         // 64 B (gap)
    float*    Xt32 = (float*)((char*)d_ws + (2u << 20));            // 2 MB
    float*    sq   = (float*)((char*)d_ws + (4u << 20));            // 32 KB
    int*      knn  = (int*)((char*)d_ws + (4u << 20) + (1u << 15)); // 256 KB
    u64*      part = (u64*)((char*)d_ws + (5u << 20));              // 4 MB

    hipMemsetAsync(bar, 0, 64, stream);   // zero barrier state each iteration
    hipLaunchKernelGGL(fused_kernel, dim3(GRID), dim3(256), 0, stream,
                       inp, crd, out, XtH, Xt32, sq, knn, part, bar);
}

// Round 20
// 162.685 us; speedup vs baseline: 3.1043x; 3.1043x over previous
//
#include <hip/hip_runtime.h>

#define F      8192
#define KD     64     // coordinate dimensionality
#define NB     8      // neighbors
#define WROWS  32     // rows per block (R13: 16 regressed 54.7->75.8us; 32 verified)
#define MKEEP  16     // per-(row,quarter) approx list length (superset of top-8)
#define JQ     4      // column quarters
#define CPR    64     // cols per block-round (4 waves x 16)
#define NROUND ((F / JQ) / CPR)   // 32
#define CAP    96     // per-row candidate buffer capacity per fold interval
#define MARGIN 0.25f  // >= 2x max |d_approx - d_exact| (fp16 worst-case ~0.08)

typedef unsigned long long u64;
typedef unsigned short ushort_t;
typedef __attribute__((ext_vector_type(8))) _Float16 f16x8;  // 8 f16 = 4 VGPRs
typedef __attribute__((ext_vector_type(4))) float f32x4;

__device__ __forceinline__ u64 pack64(float d, int j) {
    // d >= 0 -> f32 bits order-preserving; u64 ascending == lex (d, j)
    return ((u64)__float_as_uint(d) << 32) | (unsigned)j;
}

// ---------------------------------------------------------------------------
// DPP-based 16-lane exchanges (R5-verified). row_shr:N = dest[i] <- src[i-N];
// row_shl:N = dest[i] <- src[i+N]; quad_perm/mirror direction-symmetric.
// ---------------------------------------------------------------------------
template<int CTRL>
__device__ __forceinline__ u64 dpp_u64(u64 x) {
    unsigned lo = (unsigned)x, hi = (unsigned)(x >> 32);
    lo = (unsigned)__builtin_amdgcn_update_dpp(0, (int)lo, CTRL, 0xF, 0xF, true);
    hi = (unsigned)__builtin_amdgcn_update_dpp(0, (int)hi, CTRL, 0xF, 0xF, true);
    return ((u64)hi << 32) | lo;
}
__device__ __forceinline__ u64 swap_xor1(u64 x) { return dpp_u64<0xB1>(x); }
__device__ __forceinline__ u64 swap_xor2(u64 x) { return dpp_u64<0x4E>(x); }
__device__ __forceinline__ u64 swap_xor4(u64 x, int n) {
    u64 shr = dpp_u64<0x114>(x);   // src[n-4]
    u64 shl = dpp_u64<0x104>(x);   // src[n+4]
    return (n & 4) ? shr : shl;
}
__device__ __forceinline__ u64 swap_xor8(u64 x, int n) {
    u64 shr = dpp_u64<0x118>(x);   // src[n-8]
    u64 shl = dpp_u64<0x108>(x);   // src[n+8]
    return (n & 8) ? shr : shl;
}
__device__ __forceinline__ u64 swap_mirror(u64 x) { return dpp_u64<0x140>(x); }
// cross-quad exchange within a 32-lane half: ds_swizzle BitMode xor 16 (0x401F)
__device__ __forceinline__ u64 swz_xor16(u64 x) {
    unsigned lo = (unsigned)__builtin_amdgcn_ds_swizzle((int)(unsigned)x, 0x401F);
    unsigned hi = (unsigned)__builtin_amdgcn_ds_swizzle((int)(x >> 32), 0x401F);
    return ((u64)hi << 32) | lo;
}

// compare-exchange stages (ascending bitonic over lanes n=0..15)
#define CEK(x, J, K, SW)                                                      \
    { u64 px = SW; bool wmin = ((n & (J)) == 0) == ((n & (K)) == 0);          \
      x = (wmin == (px < x)) ? px : x; }
#define CEA(L, J, SW)                                                         \
    { u64 pl = SW; bool wmin = ((n & (J)) == 0);                              \
      L = (wmin == (pl < L)) ? pl : L; }
#define SORT16(x)                                                             \
    CEK(x, 1, 2,  swap_xor1(x))                                               \
    CEK(x, 2, 4,  swap_xor2(x))    CEK(x, 1, 4,  swap_xor1(x))                \
    CEK(x, 4, 8,  swap_xor4(x,n))  CEK(x, 2, 8,  swap_xor2(x))                \
    CEK(x, 1, 8,  swap_xor1(x))                                               \
    CEK(x, 8, 16, swap_xor8(x,n))  CEK(x, 4, 16, swap_xor4(x,n))              \
    CEK(x, 2, 16, swap_xor2(x))    CEK(x, 1, 16, swap_xor1(x))
// merge-with-descending-partner then 4-stage clean (list stays sorted asc)
#define MERGECLEAN(x, Y)                                                      \
    { u64 y = (Y); x = (y < x) ? y : x;                                       \
      CEA(x, 8, swap_xor8(x, n))                                              \
      CEA(x, 4, swap_xor4(x, n))                                              \
      CEA(x, 2, swap_xor2(x))                                                 \
      CEA(x, 1, swap_xor1(x)) }

// ---------------------------------------------------------------------------
// Kernel 1: prep. sq (exact ascending-k fmaf chain — recheck uses the same
// chain so dot(i,i)==sq[i] bit-exact => d(i,i)==0), transposed fp16 XtH
// (fp16 single product verified R8: passed, absmax 0), transposed fp32 Xt32
// for recheck.
// ---------------------------------------------------------------------------
__global__ __launch_bounds__(256) void prep_kernel(const float* __restrict__ crd,
                                                   float* __restrict__ sq,
                                                   ushort_t* __restrict__ XtH,
                                                   float* __restrict__ Xt32) {
    const int f = blockIdx.x * 256 + threadIdx.x;
    float acc = 0.f;
#pragma unroll
    for (int kb = 0; kb < 8; ++kb) {
        ushort_t hb[8];
        float    xv[8];
#pragma unroll
        for (int u = 0; u < 8; ++u) {
            int k = kb * 8 + u;
            float x = crd[k * F + f];
            acc = fmaf(x, x, acc);
            hb[u] = __builtin_bit_cast(ushort_t, (_Float16)x);  // RTN f32->f16
            xv[u] = x;
        }
        *(uint4*)&XtH[(size_t)f * KD + kb * 8] = *(const uint4*)hb;
        *(float4*)&Xt32[(size_t)f * KD + kb * 8]     = *(const float4*)&xv[0];
        *(float4*)&Xt32[(size_t)f * KD + kb * 8 + 4] = *(const float4*)&xv[4];
    }
    sq[f] = acc;
}

// ---------------------------------------------------------------------------
// Kernel 2: MFMA distance + approx top-16 per (row, col-quarter).
// EXACT R8/R16-verified version (54.7-55.5us): WROWS=32, 2 A-tiles, 4 MFMAs/
// round, 1024 blocks = 4/CU. R13 (8/CU) and R17-19 (fusion) both regressed;
// this is the measured optimum for this phase.
// ---------------------------------------------------------------------------
__global__ __launch_bounds__(256, 4) void knn_mfma(const ushort_t* __restrict__ XtH,
                                                   const float* __restrict__ sq,
                                                   u64* __restrict__ part) {
    __shared__ u64 buf[WROWS][CAP + 1];     // 24.8 KB
    __shared__ u64 lst[WROWS][MKEEP + 1];   // 4.4 KB
    __shared__ __align__(16) float thr[WROWS];
    __shared__ int cnt[WROWS];

    const int tid  = threadIdx.x;
    const int wave = tid >> 6;
    const int tx   = tid & 63;
    const int quad = tx >> 4;
    const int n    = tx & 15;
    const int blockRow = (blockIdx.x >> 2) * WROWS;
    const int jq    = blockIdx.x & 3;
    const int jbase = jq * (F / JQ);

    if (tid < WROWS) { cnt[tid] = 0; thr[tid] = __int_as_float(0x7f800000); }
#pragma unroll
    for (int e = tid; e < WROWS * MKEEP; e += 256) lst[e >> 4][e & 15] = ~0ULL;
    __syncthreads();

    // A fragments for both 16-row tiles, resident all sweep
    const size_t a0 = (size_t)(blockRow + n) * KD + quad * 8;
    const size_t a1 = (size_t)(blockRow + 16 + n) * KD + quad * 8;
    const f16x8 a0h0 = *(const f16x8*)(XtH + a0), a0h1 = *(const f16x8*)(XtH + a0 + 32);
    const f16x8 a1h0 = *(const f16x8*)(XtH + a1), a1h1 = *(const f16x8*)(XtH + a1 + 32);
    const f32x4 sqi0 = *(const f32x4*)&sq[blockRow + quad * 4];
    const f32x4 sqi1 = *(const f32x4*)&sq[blockRow + 16 + quad * 4];
    f32x4 pre0, pre1;   // 0.5*(sqi - thr); -inf => accept-all
#pragma unroll
    for (int r = 0; r < 4; ++r) { pre0[r] = -__int_as_float(0x7f800000);
                                  pre1[r] = -__int_as_float(0x7f800000); }

    const int laneCol = wave * 16 + n;    // col offset within a round's 64

#define LOADB(H0, H1, SJ, RND)                                                \
    {   int jc = jbase + (RND) * CPR + laneCol;                               \
        size_t bo = (size_t)jc * KD + quad * 8;                               \
        H0 = *(const f16x8*)(XtH + bo); H1 = *(const f16x8*)(XtH + bo + 32);  \
        SJ = sq[jc]; }

#define MFMABODY(H0, H1)                                                      \
        f32x4 za0 = {0,0,0,0}, za1 = {0,0,0,0};                               \
        za0 = __builtin_amdgcn_mfma_f32_16x16x32_f16(a0h0, H0, za0, 0, 0, 0); \
        za0 = __builtin_amdgcn_mfma_f32_16x16x32_f16(a0h1, H1, za0, 0, 0, 0); \
        za1 = __builtin_amdgcn_mfma_f32_16x16x32_f16(a1h0, H0, za1, 0, 0, 0); \
        za1 = __builtin_amdgcn_mfma_f32_16x16x32_f16(a1h1, H1, za1, 0, 0, 0);

// round 0: accept-all, deterministic slot = laneCol (no atomics)
#define PROCESS0(H0, H1, SJ, RND)                                             \
    {   MFMABODY(H0, H1)                                                      \
        const int jc = jbase + (RND) * CPR + laneCol;                         \
        _Pragma("unroll")                                                     \
        for (int r = 0; r < 4; ++r) {                                         \
            float d0 = fmaxf((sqi0[r] + SJ) - 2.f * za0[r], 0.f);             \
            buf[quad * 4 + r][laneCol] = pack64(d0, jc);                      \
            float d1 = fmaxf((sqi1[r] + SJ) - 2.f * za1[r], 0.f);             \
            buf[16 + quad * 4 + r][laneCol] = pack64(d1, jc);                 \
        } }

#define PROCESS(H0, H1, SJ, RND)                                              \
    {   MFMABODY(H0, H1)                                                      \
        const int jc = jbase + (RND) * CPR + laneCol;                         \
        const float h = 0.5f * SJ;                                            \
        _Pragma("unroll")                                                     \
        for (int r = 0; r < 4; ++r) {                                         \
            float dot = za0[r];                                               \
            if (dot >= pre0[r] + h) {                                         \
                float d = fmaxf((sqi0[r] + SJ) - 2.f * dot, 0.f);             \
                int row = quad * 4 + r;                                       \
                int q = atomicAdd(&cnt[row], 1);                              \
                if (q < CAP) buf[row][q] = pack64(d, jc);                     \
            }                                                                 \
            dot = za1[r];                                                     \
            if (dot >= pre1[r] + h) {                                         \
                float d = fmaxf((sqi1[r] + SJ) - 2.f * dot, 0.f);             \
                int row = 16 + quad * 4 + r;                                  \
                int q = atomicAdd(&cnt[row], 1);                              \
                if (q < CAP) buf[row][q] = pack64(d, jc);                     \
            }                                                                 \
        } }

// Wave-parallel fold, DPP stages (R5-verified). 16 lanes per row; lane n =
// sorted slot n. 2 passes cover 32 rows. Ballot pre-skip vs pass-start
// 16th-best (conservative; list only shrinks -> skip is safe).
#define FOLD(R0)                                                              \
    {   __syncthreads();                                                      \
        _Pragma("unroll")                                                     \
        for (int p = 0; p < 2; ++p) {                                         \
            const int row = p * 16 + wave * 4 + quad;                         \
            u64 Lv = lst[row][n];                                             \
            const u64 tmax = __shfl(Lv, (tx & 48) | 15, 64);                  \
            const int nn = (R0) ? CPR : min(cnt[row], CAP);                   \
            for (int ii = 0; ii < nn; ii += 16) {                             \
                u64 x = (ii + n < nn) ? buf[row][ii + n] : ~0ULL;             \
                u64 bal = __ballot(x < tmax);                                 \
                if ((unsigned short)(bal >> (quad * 16)) == 0) continue;      \
                SORT16(x)                                                     \
                MERGECLEAN(Lv, swap_mirror(x))                                \
            }                                                                 \
            lst[row][n] = Lv;                                                 \
            if (n == NB - 1) thr[row] = __uint_as_float((unsigned)(Lv >> 32)) + MARGIN; \
            if (n == 0) cnt[row] = 0;                                         \
        }                                                                     \
        __syncthreads();                                                      \
        {   f32x4 t0 = *(const f32x4*)&thr[quad * 4];                         \
            f32x4 t1 = *(const f32x4*)&thr[16 + quad * 4];                    \
            _Pragma("unroll")                                                 \
            for (int r = 0; r < 4; ++r) {                                     \
                pre0[r] = 0.5f * (sqi0[r] - t0[r]);                           \
                pre1[r] = 0.5f * (sqi1[r] - t1[r]);                           \
            } } }

    f16x8 B0h0, B0h1, B1h0, B1h1;
    float B0sj, B1sj;
    LOADB(B0h0, B0h1, B0sj, 0)
    LOADB(B1h0, B1h1, B1sj, 1)

    PROCESS0(B0h0, B0h1, B0sj, 0)
    LOADB(B0h0, B0h1, B0sj, 2)
    FOLD(1)
    PROCESS(B1h0, B1h1, B1sj, 1)
    LOADB(B1h0, B1h1, B1sj, 3)
    FOLD(0)

    for (int rr = 2; rr < NROUND; rr += 2) {
        PROCESS(B0h0, B0h1, B0sj, rr)
        if (rr + 2 < NROUND) LOADB(B0h0, B0h1, B0sj, rr + 2)
        PROCESS(B1h0, B1h1, B1sj, rr + 1)
        if (rr + 3 < NROUND) LOADB(B1h0, B1h1, B1sj, rr + 3)
        if (((rr + 1) & (rr + 2)) == 0) FOLD(0)   // rounds 3,7,15,31
    }

    // write per-quarter top-16 lists (final fold happened at round 31)
#pragma unroll
    for (int e = tid; e < WROWS * MKEEP; e += 256) {
        int rrw = e >> 4, ss = e & 15;
        part[((size_t)jq * F + blockRow + rrw) * MKEEP + ss] = lst[rrw][ss];
    }
#undef LOADB
#undef MFMABODY
#undef PROCESS0
#undef PROCESS
#undef FOLD
}

// ---------------------------------------------------------------------------
// Kernel 3: exact recheck (R16-verified). Block = 4 rows x 64 candidates.
// Top-8 via DPP bitonic sort of 64: SORT16 per quad + quad-pair merge
// (mirror + ds_swizzle xor16) + half-pair merge (mirror + shfl_xor 32).
// Ordering identical to jax: ascending packed-u64 sort.
// ---------------------------------------------------------------------------
__global__ __launch_bounds__(256) void recheck_kernel(const float* __restrict__ Xt32,
                                                      const float* __restrict__ sq,
                                                      const u64* __restrict__ part,
                                                      int* __restrict__ knn) {
    __shared__ float A_s[4][KD];
    const int tid = threadIdx.x;
    const int rl = tid >> 6, tx = tid & 63;
    const int n  = tx & 15;
    const int i = blockIdx.x * 4 + rl;

    A_s[tid >> 6][tid & 63] = Xt32[(size_t)(blockIdx.x * 4 + (tid >> 6)) * KD + (tid & 63)];
    __syncthreads();

    u64 pc = part[((size_t)(tx >> 4) * F + i) * MKEEP + (tx & 15)];
    int j = (int)(pc & 0xffffffffu);

    const float4* b4 = (const float4*)(Xt32 + (size_t)j * KD);
    float acc = 0.f;
#pragma unroll
    for (int kk = 0; kk < KD / 4; ++kk) {
        float4 b = b4[kk];
        const float* a = &A_s[rl][kk * 4];
        acc = fmaf(a[0], b.x, acc);
        acc = fmaf(a[1], b.y, acc);
        acc = fmaf(a[2], b.z, acc);
        acc = fmaf(a[3], b.w, acc);
    }
    float d = fmaxf((sq[i] + sq[j]) - 2.f * acc, 0.f);
    u64 x = pack64(d, j);

    SORT16(x)
    MERGECLEAN(x, swz_xor16(swap_mirror(x)))
    MERGECLEAN(x, __shfl_xor(swap_mirror(x), 32, 64))

    if (tx < NB) knn[(size_t)i * NB + tx] = (int)(x & 0xffffffffu);
}

// ---------------------------------------------------------------------------
// Kernel 4: gather (R16-verified). 4 blocks per (b,c); row staged in LDS;
// int4 knn + float4 stores, coalesced.
// ---------------------------------------------------------------------------
__global__ __launch_bounds__(512) void gather_kernel(const float* __restrict__ inp,
                                                     const int* __restrict__ knn,
                                                     float* __restrict__ out) {
    __shared__ float row[F];    // 32 KB
    const int bc    = blockIdx.x >> 2;
    const int chunk = blockIdx.x & 3;
    const int tid   = threadIdx.x;

    const float4* in4  = (const float4*)(inp + (size_t)bc * F);
    float4*       row4 = (float4*)row;
#pragma unroll
    for (int i = 0; i < (F / 4) / 512; ++i) row4[i * 512 + tid] = in4[i * 512 + tid];
    __syncthreads();

    const int4* kn4 = (const int4*)knn;
    float4*     ou4 = (float4*)(out + (size_t)bc * (F * NB));

#pragma unroll
    for (int i = 0; i < 8; ++i) {
        int e = chunk * 4096 + i * 512 + tid;
        int4 idx = kn4[e];
        if (e == 0) idx.x = 0;             // flat_idx[0] hardcoded 0
        float4 o;
        o.x = row[idx.x]; o.y = row[idx.y]; o.z = row[idx.z]; o.w = row[idx.w];
        ou4[e] = o;
    }
}

extern "C" void kernel_launch(void* const* d_in, const int* in_sizes, int n_in,
                              void* d_out, int out_size, void* d_ws, size_t ws_size,
                              hipStream_t stream) {
    const float* inp = (const float*)d_in[0];   // (64,4,8192,1) fp32
    const float* crd = (const float*)d_in[1];   // (64,1,8192)  fp32
    float* out = (float*)d_out;                 // (64,4,65536,1) fp32

    ushort_t* XtH  = (ushort_t*)d_ws;                               // 1 MB (fp16)
    float*    Xt32 = (float*)((char*)d_ws + (2u << 20));            // 2 MB
    float*    sq   = (float*)((char*)d_ws + (4u << 20));            // 32 KB
    int*      knn  = (int*)((char*)d_ws + (4u << 20) + (1u << 15)); // 256 KB
    u64*      part = (u64*)((char*)d_ws + (5u << 20));              // 4 MB

    prep_kernel<<<F / 256, 256, 0, stream>>>(crd, sq, XtH, Xt32);
    knn_mfma<<<(F / WROWS) * JQ, 256, 0, stream>>>(XtH, sq, part);
    recheck_kernel<<<F / 4, 256, 0, stream>>>(Xt32, sq, part, knn);
    gather_kernel<<<256 * 4, 512, 0, stream>>>(inp, knn, out);
}